// Round 10
// baseline (601.771 us; speedup 1.0000x reference)
//
#include <hip/hip_runtime.h>
#include <hip/hip_bf16.h>

#define VOCAB 12149
#define EMB 50
#define TAGS 9
#define HID 128
#define START_TOK 7
#define BSZ 256
#define TLEN 512
#define HTOT 264   // 128 main + 4 pad + 128 dup + 4 pad (dup at dword 132)

typedef float v2f __attribute__((ext_vector_type(2)));
typedef _Float16 f16x2 __attribute__((ext_vector_type(2)));

__device__ __forceinline__ float tanh_fast(float x) {
  float e = __expf(2.0f * x);
  return 1.0f - 2.0f * __builtin_amdgcn_rcpf(e + 1.0f);
}

template<int CTRL>
__device__ __forceinline__ float dpp_mov(float x) {
  return __int_as_float(__builtin_amdgcn_update_dpp(
      0, __float_as_int(x), CTRL, 0xF, 0xF, true));
}
#define DPP_XOR1 0xB1   // quad_perm [1,0,3,2]

// exw[v][j] = sum_e emb[v][e] * enc_Wx[e][j] + enc_b[j]
__global__ __launch_bounds__(128) void exw_kernel(
    const float* __restrict__ emb, const float* __restrict__ Wx,
    const float* __restrict__ bv, float* __restrict__ exw)
{
  __shared__ float wx_s[EMB * HID];
  __shared__ float emb_s[8 * EMB];
  const int tid = threadIdx.x;
  const int v0 = blockIdx.x * 8;
  for (int idx = tid; idx < EMB * HID; idx += 128) wx_s[idx] = Wx[idx];
  for (int idx = tid; idx < 8 * EMB; idx += 128) {
    int r = idx / EMB;
    int e = idx - r * EMB;
    int v = v0 + r;
    emb_s[idx] = (v < VOCAB) ? emb[v * EMB + e] : 0.0f;
  }
  __syncthreads();
  const float bj = bv[tid];
  for (int r = 0; r < 8; ++r) {
    int v = v0 + r;
    if (v >= VOCAB) break;
    float acc = bj;
#pragma unroll
    for (int e = 0; e < EMB; ++e) acc += emb_s[r * EMB + e] * wx_s[e * HID + tid];
    exw[v * HID + tid] = acc;
  }
}

// One WG (128 thr = 2 waves) per batch row. Thread i owns h[i]; pair
// (i&~1, i|1) k-splits (q=i&1 -> k in [64q,64q+64)). h kept in TWO LDS
// copies (dup at +132 dwords) so the two broadcast read streams hit
// disjoint banks: q0 reads dwords 4c (banks 4c..4c+3), q1 reads dwords
// 196+4c (banks 4c+4..4c+7). Weights pre-swapped per lane (.x own col,
// .y partner col) so the pair-reduce is a single DPP xor1, no cndmask.
__global__ __launch_bounds__(128, 1) void rnn_kernel(
    const int* __restrict__ inputs, const int* __restrict__ labels,
    const float* __restrict__ exw,
    const float* __restrict__ encWh,
    const float* __restrict__ dembG, const float* __restrict__ decWx,
    const float* __restrict__ decWh, const float* __restrict__ decb,
    unsigned short* __restrict__ hws16)
{
  __shared__ __align__(16) float h_s[2][HTOT];
  __shared__ __align__(16) float dxw_s[TAGS * HID];
  __shared__ int tok_s[TLEN];
  __shared__ int lab_s[TLEN];

  const int tid = threadIdx.x;    // 0..127
  const int q = tid & 1;          // k-half
  const int bidx = blockIdx.x;

  for (int idx = tid; idx < TLEN; idx += 128) {
    tok_s[idx] = inputs[bidx * TLEN + idx];
    lab_s[idx] = labels[bidx * TLEN + idx];
  }
  for (int task = tid; task < TAGS * HID; task += 128) {
    int tag = task >> 7;
    int j2 = task & 127;
    float acc = decb[j2];
#pragma unroll
    for (int e = 0; e < EMB; ++e) acc += dembG[tag * EMB + e] * decWx[e * HID + j2];
    dxw_s[task] = acc;
  }
  h_s[0][tid] = 0.0f;
  h_s[0][132 + tid] = 0.0f;       // zero the dup copy too

  // ---- encoder weights: wv[kk] = { Wh[64q+kk][tid], Wh[64q+kk][tid^1] } ----
  v2f wv[64];
#pragma unroll
  for (int kk = 0; kk < 64; ++kk) {
    const float* Wrow = &encWh[(64 * q + kk) * HID];
    wv[kk] = v2f{Wrow[tid], Wrow[tid ^ 1]};
  }
  __syncthreads();

  const float* exw_i = exw + tid;
  int cur = 0;

  float xv0 = exw_i[tok_s[0] * HID];
  float xv1 = exw_i[tok_s[1] * HID];
  float xv2 = exw_i[tok_s[2] * HID];
  float xv3 = exw_i[tok_s[3] * HID];

  // ======== encoder ========
#pragma unroll 4
  for (int t = 0; t < TLEN; ++t) {
    int tn = (t + 4 < TLEN) ? t + 4 : TLEN - 1;
    float xvn = exw_i[tok_s[tn] * HID];

    const float* hb = &h_s[cur][q * 196];    // q0: main[0..63]; q1: dup[64..127]
    float aO0 = 0.f, aO1 = 0.f, aP0 = 0.f, aP1 = 0.f;
#pragma unroll
    for (int c = 0; c < 16; ++c) {
      float4 hv = *(const float4*)&hb[4 * c];
      aO0 += hv.x * wv[4 * c + 0].x;  aP0 += hv.x * wv[4 * c + 0].y;
      aO1 += hv.y * wv[4 * c + 1].x;  aP1 += hv.y * wv[4 * c + 1].y;
      aO0 += hv.z * wv[4 * c + 2].x;  aP0 += hv.z * wv[4 * c + 2].y;
      aO1 += hv.w * wv[4 * c + 3].x;  aP1 += hv.w * wv[4 * c + 3].y;
    }
    float v = (aO0 + aO1) + dpp_mov<DPP_XOR1>(aP0 + aP1);
    float hn = tanh_fast(v + xv0);
    h_s[cur ^ 1][tid] = hn;
    h_s[cur ^ 1][132 + tid] = hn;
    __syncthreads();
    cur ^= 1;
    xv0 = xv1; xv1 = xv2; xv2 = xv3; xv3 = xvn;
  }

  // ---- decoder weights (same registers/layout) ----
#pragma unroll
  for (int kk = 0; kk < 64; ++kk) {
    const float* Wrow = &decWh[(64 * q + kk) * HID];
    wv[kk] = v2f{Wrow[tid], Wrow[tid ^ 1]};
  }

  // ======== decoder ========
  unsigned short* hrow = hws16 + (size_t)(bidx * TLEN) * HID + tid;
  float xvD = dxw_s[START_TOK * HID + tid];
#pragma unroll 2
  for (int t = 0; t < TLEN; ++t) {
    int labn = lab_s[t];                       // dec_in[t+1] = label[t]
    float xvDn = dxw_s[labn * HID + tid];      // prefetch next step's xv

    const float* hb = &h_s[cur][q * 196];
    float aO0 = 0.f, aO1 = 0.f, aP0 = 0.f, aP1 = 0.f;
#pragma unroll
    for (int c = 0; c < 16; ++c) {
      float4 hv = *(const float4*)&hb[4 * c];
      aO0 += hv.x * wv[4 * c + 0].x;  aP0 += hv.x * wv[4 * c + 0].y;
      aO1 += hv.y * wv[4 * c + 1].x;  aP1 += hv.y * wv[4 * c + 1].y;
      aO0 += hv.z * wv[4 * c + 2].x;  aP0 += hv.z * wv[4 * c + 2].y;
      aO1 += hv.w * wv[4 * c + 3].x;  aP1 += hv.w * wv[4 * c + 3].y;
    }
    float v = (aO0 + aO1) + dpp_mov<DPP_XOR1>(aP0 + aP1);
    float hn = tanh_fast(v + xvD);
    h_s[cur ^ 1][tid] = hn;
    h_s[cur ^ 1][132 + tid] = hn;
    hrow[(size_t)t * HID] =
        __builtin_bit_cast(unsigned short, (_Float16)hn);
    __syncthreads();
    cur ^= 1;
    xvD = xvDn;
  }
}

// out[t][o] = h[t] @ W + b; h stored as 128 f16 per row
__global__ __launch_bounds__(256) void proj_kernel(
    const unsigned short* __restrict__ hws16, const float* __restrict__ W,
    const float* __restrict__ bout, float* __restrict__ out)
{
  __shared__ float Wt_s[TAGS][HID];
  __shared__ float bo_s[TAGS];
  const int tid = threadIdx.x;
  for (int idx = tid; idx < TAGS * HID; idx += 256) {
    int o = idx >> 7;
    int j2 = idx & 127;
    Wt_s[o][j2] = W[j2 * TAGS + o];
  }
  if (tid < TAGS) bo_s[tid] = bout[tid];
  __syncthreads();

  const int gt = blockIdx.x * 256 + tid;       // 0 .. B*T-1
  const uint2* hrow = (const uint2*)(hws16 + (size_t)gt * HID);
  float acc[TAGS];
#pragma unroll
  for (int o = 0; o < TAGS; ++o) acc[o] = bo_s[o];
#pragma unroll
  for (int c = 0; c < 32; ++c) {               // 32 chunks x 4 f16 = 128 = HID
    uint2 u = hrow[c];
    f16x2 p0 = __builtin_bit_cast(f16x2, u.x);
    f16x2 p1 = __builtin_bit_cast(f16x2, u.y);
    float h0 = (float)p0.x, h1 = (float)p0.y;
    float h2v = (float)p1.x, h3 = (float)p1.y;
#pragma unroll
    for (int o = 0; o < TAGS; ++o) {
      const float* wr = &Wt_s[o][4 * c];
      acc[o] += h0 * wr[0] + h1 * wr[1] + h2v * wr[2] + h3 * wr[3];
    }
  }
  float* op = &out[(size_t)gt * TAGS];
#pragma unroll
  for (int o = 0; o < TAGS; ++o) op[o] = acc[o];
}

extern "C" void kernel_launch(void* const* d_in, const int* in_sizes, int n_in,
                              void* d_out, int out_size, void* d_ws, size_t ws_size,
                              hipStream_t stream) {
  const int* inputs   = (const int*)d_in[0];
  const int* labels   = (const int*)d_in[1];
  const float* emb    = (const float*)d_in[2];
  const float* encWx  = (const float*)d_in[3];
  const float* encWh  = (const float*)d_in[4];
  const float* encb   = (const float*)d_in[5];
  const float* demb   = (const float*)d_in[6];
  const float* decWx  = (const float*)d_in[7];
  const float* decWh  = (const float*)d_in[8];
  const float* decb   = (const float*)d_in[9];
  const float* W      = (const float*)d_in[10];
  const float* bo     = (const float*)d_in[11];
  float* out = (float*)d_out;

  const size_t exw_floats = (size_t)VOCAB * HID;                 // 6.22 MB
  float* exw = (float*)d_ws;
  unsigned short* hws16 = (unsigned short*)((float*)d_ws + exw_floats);
  // needed: 6.22 MB + B*T*HID*2 = 23 MB total (ws >= 40 MB proven in round 6)

  exw_kernel<<<(VOCAB + 7) / 8, 128, 0, stream>>>(emb, encWx, encb, exw);
  rnn_kernel<<<BSZ, 128, 0, stream>>>(inputs, labels, exw, encWh,
                                      demb, decWx, decWh, decb, hws16);
  proj_kernel<<<(BSZ * TLEN) / 256, 256, 0, stream>>>(hws16, W, bo, out);
}

// Round 11
// 464.702 us; speedup vs baseline: 1.2950x; 1.2950x over previous
//
#include <hip/hip_runtime.h>
#include <hip/hip_bf16.h>

#define VOCAB 12149
#define EMB 50
#define TAGS 9
#define HID 128
#define START_TOK 7
#define BSZ 256
#define TLEN 512

typedef float v2f __attribute__((ext_vector_type(2)));
typedef _Float16 f16x2 __attribute__((ext_vector_type(2)));

__device__ __forceinline__ float tanh_fast(float x) {
  float e = __expf(2.0f * x);
  return 1.0f - 2.0f * __builtin_amdgcn_rcpf(e + 1.0f);
}

template<int CTRL>
__device__ __forceinline__ float dpp_mov(float x) {
  return __int_as_float(__builtin_amdgcn_update_dpp(
      0, __float_as_int(x), CTRL, 0xF, 0xF, true));
}
#define DPP_XOR1 0xB1   // quad_perm [1,0,3,2]

// exw[v][j] = sum_e emb[v][e] * enc_Wx[e][j] + enc_b[j]
__global__ __launch_bounds__(128) void exw_kernel(
    const float* __restrict__ emb, const float* __restrict__ Wx,
    const float* __restrict__ bv, float* __restrict__ exw)
{
  __shared__ float wx_s[EMB * HID];
  __shared__ float emb_s[8 * EMB];
  const int tid = threadIdx.x;
  const int v0 = blockIdx.x * 8;
  for (int idx = tid; idx < EMB * HID; idx += 128) wx_s[idx] = Wx[idx];
  for (int idx = tid; idx < 8 * EMB; idx += 128) {
    int r = idx / EMB;
    int e = idx - r * EMB;
    int v = v0 + r;
    emb_s[idx] = (v < VOCAB) ? emb[v * EMB + e] : 0.0f;
  }
  __syncthreads();
  const float bj = bv[tid];
  for (int r = 0; r < 8; ++r) {
    int v = v0 + r;
    if (v >= VOCAB) break;
    float acc = bj;
#pragma unroll
    for (int e = 0; e < EMB; ++e) acc += emb_s[r * EMB + e] * wx_s[e * HID + tid];
    exw[v * HID + tid] = acc;
  }
}

// One WG (128 thr = 2 waves) per batch row — r8 structure. Thread i owns
// h[i]; pair (i&~1, i|1) k-splits (q=i&1 -> k in [64q,64q+64)). Global ops
// batched per 8/16-step blocks so the pre-barrier vmcnt drain amortizes.
// Decoder h written t-major: hws16[(b*HID + j)*TLEN + t].
__global__ __launch_bounds__(128, 1) void rnn_kernel(
    const int* __restrict__ inputs, const int* __restrict__ labels,
    const float* __restrict__ exw,
    const float* __restrict__ encWh,
    const float* __restrict__ dembG, const float* __restrict__ decWx,
    const float* __restrict__ decWh, const float* __restrict__ decb,
    unsigned short* __restrict__ hws16)
{
  __shared__ __align__(16) float h_s[2][HID];
  __shared__ __align__(16) float dxw_s[TAGS * HID];
  __shared__ int tok_s[TLEN];
  __shared__ int lab_s[TLEN];

  const int tid = threadIdx.x;    // 0..127
  const int q = tid & 1;          // k-half
  const int jE = tid & ~1;        // even column of the owned pair
  const int bidx = blockIdx.x;

  for (int idx = tid; idx < TLEN; idx += 128) {
    tok_s[idx] = inputs[bidx * TLEN + idx];
    lab_s[idx] = labels[bidx * TLEN + idx];
  }
  for (int task = tid; task < TAGS * HID; task += 128) {
    int tag = task >> 7;
    int j2 = task & 127;
    float acc = decb[j2];
#pragma unroll
    for (int e = 0; e < EMB; ++e) acc += dembG[tag * EMB + e] * decWx[e * HID + j2];
    dxw_s[task] = acc;
  }
  h_s[0][tid] = 0.0f;

  v2f wv[64];
#pragma unroll
  for (int kk = 0; kk < 64; ++kk)
    wv[kk] = *(const v2f*)&encWh[(64 * q + kk) * HID + jE];
  __syncthreads();

  const float* exw_i = exw + tid;
  int cur = 0;

  // ======== encoder: 8-step blocks, xv loads batched per block ========
  float xcur[8], xnext[8];
#pragma unroll
  for (int u = 0; u < 8; ++u) xcur[u] = exw_i[tok_s[u] * HID];

  for (int tb = 0; tb < TLEN; tb += 8) {
    // issue next block's 8 gathers (drained ~once per 8 barriers)
#pragma unroll
    for (int u = 0; u < 8; ++u) {
      int idx = tb + 8 + u;
      if (idx > TLEN - 1) idx = TLEN - 1;
      xnext[u] = exw_i[tok_s[idx] * HID];
    }
#pragma unroll
    for (int u = 0; u < 8; ++u) {
      const float* hb = &h_s[cur][64 * q];
      float aE0 = 0.f, aE1 = 0.f, aO0 = 0.f, aO1 = 0.f;
#pragma unroll
      for (int c = 0; c < 16; ++c) {
        float4 hv = *(const float4*)&hb[4 * c];
        aE0 += hv.x * wv[4 * c + 0].x;  aO0 += hv.x * wv[4 * c + 0].y;
        aE1 += hv.y * wv[4 * c + 1].x;  aO1 += hv.y * wv[4 * c + 1].y;
        aE0 += hv.z * wv[4 * c + 2].x;  aO0 += hv.z * wv[4 * c + 2].y;
        aE1 += hv.w * wv[4 * c + 3].x;  aO1 += hv.w * wv[4 * c + 3].y;
      }
      float aE = aE0 + aE1, aO = aO0 + aO1;
      float keep = q ? aO : aE;
      float send = q ? aE : aO;
      float v = keep + dpp_mov<DPP_XOR1>(send);
      float hn = tanh_fast(v + xcur[u]);
      h_s[cur ^ 1][tid] = hn;
      __syncthreads();
      cur ^= 1;
    }
#pragma unroll
    for (int u = 0; u < 8; ++u) xcur[u] = xnext[u];
  }

  // ---- decoder weights ----
#pragma unroll
  for (int kk = 0; kk < 64; ++kk)
    wv[kk] = *(const v2f*)&decWh[(64 * q + kk) * HID + jE];

  // ======== decoder: 16-step blocks, f16 h packed in regs, 2 stores/block ====
  unsigned int* hbase =
      (unsigned int*)(hws16 + ((size_t)bidx * HID + tid) * TLEN);
  float xvD = dxw_s[START_TOK * HID + tid];

  for (int tb = 0; tb < TLEN; tb += 16) {
    unsigned int st[8];
    unsigned int lo = 0;
#pragma unroll
    for (int u = 0; u < 16; ++u) {
      const int t = tb + u;
      int labn = lab_s[t];                       // dec_in[t+1] = label[t]
      float xvDn = dxw_s[labn * HID + tid];      // prefetch next step's xv (LDS)

      const float* hb = &h_s[cur][64 * q];
      float aE0 = 0.f, aE1 = 0.f, aO0 = 0.f, aO1 = 0.f;
#pragma unroll
      for (int c = 0; c < 16; ++c) {
        float4 hv = *(const float4*)&hb[4 * c];
        aE0 += hv.x * wv[4 * c + 0].x;  aO0 += hv.x * wv[4 * c + 0].y;
        aE1 += hv.y * wv[4 * c + 1].x;  aO1 += hv.y * wv[4 * c + 1].y;
        aE0 += hv.z * wv[4 * c + 2].x;  aO0 += hv.z * wv[4 * c + 2].y;
        aE1 += hv.w * wv[4 * c + 3].x;  aO1 += hv.w * wv[4 * c + 3].y;
      }
      float aE = aE0 + aE1, aO = aO0 + aO1;
      float keep = q ? aO : aE;
      float send = q ? aE : aO;
      float v = keep + dpp_mov<DPP_XOR1>(send);
      float hn = tanh_fast(v + xvD);
      h_s[cur ^ 1][tid] = hn;

      unsigned int hu =
          (unsigned int)__builtin_bit_cast(unsigned short, (_Float16)hn);
      if ((u & 1) == 0) lo = hu;
      else              st[u >> 1] = lo | (hu << 16);

      __syncthreads();
      cur ^= 1;
      xvD = xvDn;
    }
    // flush 16 steps = 8 dwords (t-major, contiguous per thread)
    *(uint4*)&hbase[tb / 2]     = uint4{st[0], st[1], st[2], st[3]};
    *(uint4*)&hbase[tb / 2 + 4] = uint4{st[4], st[5], st[6], st[7]};
  }
}

// out[b][t][o] = h[b][t] @ W + b; h stored t-major: hws16[(b*HID+j)*TLEN+t].
// One block per b (128 threads); tiles of 128 t staged through LDS.
__global__ __launch_bounds__(128) void proj_kernel(
    const unsigned short* __restrict__ hws16, const float* __restrict__ W,
    const float* __restrict__ bout, float* __restrict__ out)
{
  __shared__ float Wt_s[TAGS][HID];
  __shared__ float bo_s[TAGS];
  __shared__ unsigned int htile[HID][64];   // 128 j x 128 t (f16 pairs), 32KB

  const int tid = threadIdx.x;              // 0..127
  const int b = blockIdx.x;
  for (int idx = tid; idx < TAGS * HID; idx += 128) {
    int o = idx >> 7;
    int j2 = idx & 127;
    Wt_s[o][j2] = W[j2 * TAGS + o];
  }
  if (tid < TAGS) bo_s[tid] = bout[tid];

  for (int tt = 0; tt < TLEN; tt += 128) {
    __syncthreads();
    // stage: 128 j-rows x 32 uint4 per row (128 t = 64 dwords = 16 uint4)
    // each thread loads 16 uint4: 8 iterations x (j = tid, parts)
    for (int i = tid; i < HID * 16; i += 128) {
      int j = i >> 4;
      int p = i & 15;
      const uint4 u = *(const uint4*)
          (hws16 + ((size_t)b * HID + j) * TLEN + tt) + 0[&p] * 0 ;
      // (placeholder removed below)
      (void)u;
    }
    // NOTE: simple scalar staging to keep indexing obviously right:
    for (int i = tid; i < HID * 64; i += 128) {
      int j = i >> 6;                      // 0..127
      int d = i & 63;                      // dword within row (2 t's)
      htile[j][d] = *(const unsigned int*)
          (hws16 + ((size_t)b * HID + j) * TLEN + tt + 2 * d);
    }
    __syncthreads();

    const int t = tid;                     // t-local 0..127
    float acc[TAGS];
#pragma unroll
    for (int o = 0; o < TAGS; ++o) acc[o] = bo_s[o];
    const int dh = t >> 1;
    const int hi = t & 1;
#pragma unroll 16
    for (int j = 0; j < HID; ++j) {
      unsigned int u = htile[j][dh];
      unsigned short us = hi ? (unsigned short)(u >> 16) : (unsigned short)u;
      float hv = (float)__builtin_bit_cast(_Float16, us);
#pragma unroll
      for (int o = 0; o < TAGS; ++o) acc[o] += hv * Wt_s[o][j];
    }
    float* op = &out[((size_t)b * TLEN + tt + t) * TAGS];
#pragma unroll
    for (int o = 0; o < TAGS; ++o) op[o] = acc[o];
  }
}

extern "C" void kernel_launch(void* const* d_in, const int* in_sizes, int n_in,
                              void* d_out, int out_size, void* d_ws, size_t ws_size,
                              hipStream_t stream) {
  const int* inputs   = (const int*)d_in[0];
  const int* labels   = (const int*)d_in[1];
  const float* emb    = (const float*)d_in[2];
  const float* encWx  = (const float*)d_in[3];
  const float* encWh  = (const float*)d_in[4];
  const float* encb   = (const float*)d_in[5];
  const float* demb   = (const float*)d_in[6];
  const float* decWx  = (const float*)d_in[7];
  const float* decWh  = (const float*)d_in[8];
  const float* decb   = (const float*)d_in[9];
  const float* W      = (const float*)d_in[10];
  const float* bo     = (const float*)d_in[11];
  float* out = (float*)d_out;

  const size_t exw_floats = (size_t)VOCAB * HID;                 // 6.22 MB
  float* exw = (float*)d_ws;
  unsigned short* hws16 = (unsigned short*)((float*)d_ws + exw_floats);
  // needed: 6.22 MB + B*T*HID*2 = 23 MB total (ws >= 40 MB proven in round 6)

  exw_kernel<<<(VOCAB + 7) / 8, 128, 0, stream>>>(emb, encWx, encb, exw);
  rnn_kernel<<<BSZ, 128, 0, stream>>>(inputs, labels, exw, encWh,
                                      demb, decWx, decWh, decb, hws16);
  proj_kernel<<<BSZ, 128, 0, stream>>>(hws16, W, bo, out);
}